// Round 12
// baseline (260.536 us; speedup 1.0000x reference)
//
#include <hip/hip_runtime.h>
#include <hip/hip_bf16.h>
#include <math.h>

#define TB 256
#define NW 4                  // waves per block
#define TPW 9                 // tiles per wave (4*9=36 >= 34 real tiles)
#define VOFFH 512             // halves of zero pad below v[0]
#define SVH 9760              // bf16 halves in sv image (max read idx 9744)
#define UMAX 81               // 8*(TPW-1)+17 fragment steps per wave

typedef __attribute__((ext_vector_type(8))) short bf16x8;
typedef __attribute__((ext_vector_type(4))) float f32x4;

__device__ __forceinline__ short f2b(float x) {
    union { __hip_bfloat16 h; short s; } u;
    u.h = __float2bfloat16(x);
    return u.s;
}

// ---- per-layer sum(bk^2) into ws[0..3] ----
__global__ __launch_bounds__(256) void y2_kernel(
    const float* __restrict__ bk0, const float* __restrict__ bk1,
    const float* __restrict__ bk2, const float* __restrict__ bk3,
    float* __restrict__ ws)
{
    const float* bks[4] = {bk0, bk1, bk2, bk3};
    const int i = blockIdx.x;
    const int L = 8192 + (i + 1) * 512;
    const float* b = bks[i];
    float s = 0.f;
    for (int n = threadIdx.x; n < L; n += 256) { float x = b[n]; s += x * x; }
    #pragma unroll
    for (int off = 32; off; off >>= 1) s += __shfl_down(s, off, 64);
    __shared__ float sp[4];
    if ((threadIdx.x & 63) == 0) sp[threadIdx.x >> 6] = s;
    __syncthreads();
    if (threadIdx.x == 0) ws[i] = sp[0] + sp[1] + sp[2] + sp[3];
}

// ---- build w-Toeplitz MFMA A-fragments into global table (row-independent) ----
__global__ __launch_bounds__(64) void prep_kernel(const float* __restrict__ w,
                                                  short* __restrict__ wtab)
{
    const int id   = blockIdx.x;          // 0..67 = layer*17 + ks
    const int layer = id / 17, ks = id % 17;
    const int lane = threadIdx.x;
    const int r    = lane & 15;
    const int kb   = ks * 32 + (lane >> 4) * 8;
    const float* wl = w + layer * 512;
    bf16x8 bb;
    #pragma unroll
    for (int jj = 0; jj < 8; ++jj) {
        const int idx = 512 + r - (kb + jj);
        const float val = (idx >= 0 && idx < 512) ? wl[idx] : 0.f;
        bb[jj] = f2b(val);
    }
    *(bf16x8*)(wtab + ((size_t)id * 64 + lane) * 8) = bb;
}

// ---- main fused kernel: one block per batch row; linear-g fragment scan ----
// launch_bounds(TB, 2): raise the scheduler's register budget so it hoists
// ds_reads deeper (R11 analysis: 3-5 in-flight reads -> ~120cy stall every
// few steps; target 10-20 in flight). Single-variable change vs R11.
__global__ __launch_bounds__(TB, 2) void hdcnn_kernel(
    const float* __restrict__ hk, const short* __restrict__ wtab,
    const float* __restrict__ bk0, const float* __restrict__ bk1,
    const float* __restrict__ bk2, const float* __restrict__ bk3,
    const float* __restrict__ y2w, float* __restrict__ out)
{
    __shared__ __align__(16) short svb[SVH];   // bf16 image of v, zero-padded
    __shared__ float sred[NW * 2];

    const int tid  = threadIdx.x;
    const int row  = blockIdx.x;
    const int lane = tid & 63;
    const int wv   = tid >> 6;
    const int jn   = lane & 15;
    const int kq   = lane >> 4;
    const int t0   = wv * TPW;                 // first tile of this wave

    // zero-fill sv image
    {
        int* svi = (int*)svb;
        for (int i = tid; i < SVH / 2; i += TB) svi[i] = 0;
    }
    __syncthreads();

    // layer-0 ingest: hk row -> bf16 at VOFFH
    {
        const float4* hrow = (const float4*)(hk + (size_t)row * 8192);
        for (int j = tid; j < 1024; j += TB) {
            float4 x0 = hrow[2 * j];
            float4 x1 = hrow[2 * j + 1];
            bf16x8 p;
            p[0] = f2b(x0.x); p[1] = f2b(x0.y); p[2] = f2b(x0.z); p[3] = f2b(x0.w);
            p[4] = f2b(x1.x); p[5] = f2b(x1.y); p[6] = f2b(x1.z); p[7] = f2b(x1.w);
            *(bf16x8*)(svb + VOFFH + 8 * j) = p;
        }
    }

    const int vbase = t0 * 256 + 16 * jn + 8 * kq;   // svb half-index base

    for (int layer = 0; layer < 4; ++layer) {
        const float* __restrict__ bk = (layer == 0) ? bk0 : (layer == 1) ? bk1
                                     : (layer == 2) ? bk2 : bk3;

        // w-Toeplitz A-fragments: 17 coalesced b128 loads from L2-hot table
        const short* wt = wtab + (size_t)layer * 8704 + lane * 8;
        bf16x8 wf[17];
        #pragma unroll
        for (int ks = 0; ks < 17; ++ks) wf[ks] = *(const bf16x8*)(wt + ks * 512);

        __syncthreads();   // svb (ingest or prev writeback) visible to all

        // linear fragment scan: g = 8*t0 + u; frag feeds tiles dt with ks=u-8*dt
        // Fully static: no runtime guards inside (R6 lesson: guard -> scratch spill).
        f32x4 acc[TPW];
        #pragma unroll
        for (int dt = 0; dt < TPW; ++dt) acc[dt] = (f32x4){0.f, 0.f, 0.f, 0.f};

        #pragma unroll
        for (int u = 0; u < UMAX; ++u) {
            bf16x8 vf = *(const bf16x8*)(svb + vbase + 32 * u);
            const int dtlo = (u > 16) ? ((u - 9) >> 3) : 0;
            const int dthi = ((u >> 3) < TPW - 1) ? (u >> 3) : (TPW - 1);
            #pragma unroll
            for (int dt = dtlo; dt <= dthi; ++dt)
                acc[dt] = __builtin_amdgcn_mfma_f32_16x16x32_bf16(
                    wf[u - 8 * dt], vf, acc[dt], 0, 0, 0);
        }

        // row scalars: sum(conv^2), sum(conv*bk)
        float sum2 = 0.f, sxy = 0.f;
        #pragma unroll
        for (int dt = 0; dt < TPW; ++dt) {
            if (t0 + dt < 34) {
                const int nb = (t0 + dt) * 256 + 16 * jn + 4 * kq;
                float4 b4 = *(const float4*)(bk + nb);
                sum2 = fmaf(acc[dt][0], acc[dt][0], sum2);
                sum2 = fmaf(acc[dt][1], acc[dt][1], sum2);
                sum2 = fmaf(acc[dt][2], acc[dt][2], sum2);
                sum2 = fmaf(acc[dt][3], acc[dt][3], sum2);
                sxy  = fmaf(acc[dt][0], b4.x, sxy);
                sxy  = fmaf(acc[dt][1], b4.y, sxy);
                sxy  = fmaf(acc[dt][2], b4.z, sxy);
                sxy  = fmaf(acc[dt][3], b4.w, sxy);
            }
        }
        #pragma unroll
        for (int off = 32; off; off >>= 1) {
            sum2 += __shfl_down(sum2, off, 64);
            sxy  += __shfl_down(sxy,  off, 64);
        }
        if (lane == 0) { sred[wv * 2] = sum2; sred[wv * 2 + 1] = sxy; }
        __syncthreads();
        float un2 = 0.f, xys = 0.f;
        #pragma unroll
        for (int i = 0; i < NW; ++i) { un2 += sred[2 * i]; xys += sred[2 * i + 1]; }

        // hyperbolic scalars -> alpha, beta
        const float Cc  = 1e-12f;
        const float un  = sqrtf(un2);
        const float unc = fmaxf(un, 1e-15f);
        const float aa  = 1e-6f * unc;            // sqrt(c) * ||u||
        const float f   = tanhf(aa) / aa;         // expmap0 scale
        const float hn  = f * un;
        const float hnc = fmaxf(hn, 1e-15f);
        const float maxn = (1.0f - 0.004f) * 1.0e6f;
        const float s   = (hnc > maxn) ? f * (maxn / hnc) : f;  // proj scale
        const float x2  = s * s * un2;
        const float xy  = s * xys;
        const float y2  = y2w[layer];
        const float t2c = 2.f * Cc * xy;
        const float A   = 1.f + t2c + Cc * y2;
        const float B   = 1.f - Cc * x2;
        float D = 1.f + t2c + Cc * Cc * x2 * y2;
        D = fmaxf(D, 1e-15f);
        const float alpha = A * s / D;
        const float beta  = B / D;

        if (layer < 3) {
            // next v = relu(alpha*conv + beta*bk)[0:8192] as bf16
            #pragma unroll
            for (int dt = 0; dt < TPW; ++dt) {
                if (t0 + dt < 32) {
                    const int nb = (t0 + dt) * 256 + 16 * jn + 4 * kq;
                    float4 b4 = *(const float4*)(bk + nb);
                    short4 o;
                    o.x = f2b(fmaxf(alpha * acc[dt][0] + beta * b4.x, 0.f));
                    o.y = f2b(fmaxf(alpha * acc[dt][1] + beta * b4.y, 0.f));
                    o.z = f2b(fmaxf(alpha * acc[dt][2] + beta * b4.z, 0.f));
                    o.w = f2b(fmaxf(alpha * acc[dt][3] + beta * b4.w, 0.f));
                    *(short4*)(svb + VOFFH + nb) = o;
                }
            }
            // next layer's top barrier orders these writes before reads
        } else {
            float* orow = out + (size_t)row * 10240;
            #pragma unroll
            for (int dt = 0; dt < TPW; ++dt) {
                if (t0 + dt < 34) {
                    const int nb = (t0 + dt) * 256 + 16 * jn + 4 * kq;
                    float4 b4 = *(const float4*)(bk + nb);
                    float4 o;
                    o.x = fmaxf(alpha * acc[dt][0] + beta * b4.x, 0.f);
                    o.y = fmaxf(alpha * acc[dt][1] + beta * b4.y, 0.f);
                    o.z = fmaxf(alpha * acc[dt][2] + beta * b4.z, 0.f);
                    o.w = fmaxf(alpha * acc[dt][3] + beta * b4.w, 0.f);
                    *(float4*)(orow + nb) = o;
                }
            }
            for (int n = 8704 + 4 * tid; n < 10240; n += 4 * TB) {
                float4 b4 = *(const float4*)(bk + n);
                float4 o;
                o.x = fmaxf(beta * b4.x, 0.f);
                o.y = fmaxf(beta * b4.y, 0.f);
                o.z = fmaxf(beta * b4.z, 0.f);
                o.w = fmaxf(beta * b4.w, 0.f);
                *(float4*)(orow + n) = o;
            }
        }
    }
}

extern "C" void kernel_launch(void* const* d_in, const int* in_sizes, int n_in,
                              void* d_out, int out_size, void* d_ws, size_t ws_size,
                              hipStream_t stream) {
    const float* hk  = (const float*)d_in[0];
    const float* w   = (const float*)d_in[1];
    const float* bk0 = (const float*)d_in[2];
    const float* bk1 = (const float*)d_in[3];
    const float* bk2 = (const float*)d_in[4];
    const float* bk3 = (const float*)d_in[5];
    float* out = (float*)d_out;
    float* ws  = (float*)d_ws;          // [0..3]: y2 sums; +4: w-frag table
    short* wtab = (short*)(ws + 4);     // 68*64*8 halves = 69632 B

    y2_kernel<<<4, 256, 0, stream>>>(bk0, bk1, bk2, bk3, ws);
    prep_kernel<<<68, 64, 0, stream>>>(w, wtab);
    hdcnn_kernel<<<4096, TB, 0, stream>>>(hk, wtab, bk0, bk1, bk2, bk3, ws, out);
}

// Round 13
// 251.166 us; speedup vs baseline: 1.0373x; 1.0373x over previous
//
#include <hip/hip_runtime.h>
#include <hip/hip_bf16.h>
#include <math.h>

#define TB 256
#define NW 4                  // waves per block
#define TPW 9                 // tiles per wave (4*9=36 >= 34 real tiles)
#define VOFFH 512             // halves of zero pad below v[0]
#define SVH 9760              // bf16 halves in sv image (max read idx 9744)
#define UMAX 81               // 8*(TPW-1)+17 fragment steps per wave

typedef __attribute__((ext_vector_type(8))) short bf16x8;
typedef __attribute__((ext_vector_type(4))) float f32x4;

__device__ __forceinline__ short f2b(float x) {
    union { __hip_bfloat16 h; short s; } u;
    u.h = __float2bfloat16(x);
    return u.s;
}

// ---- per-layer sum(bk^2) into ws[0..3] ----
__global__ __launch_bounds__(256) void y2_kernel(
    const float* __restrict__ bk0, const float* __restrict__ bk1,
    const float* __restrict__ bk2, const float* __restrict__ bk3,
    float* __restrict__ ws)
{
    const float* bks[4] = {bk0, bk1, bk2, bk3};
    const int i = blockIdx.x;
    const int L = 8192 + (i + 1) * 512;
    const float* b = bks[i];
    float s = 0.f;
    for (int n = threadIdx.x; n < L; n += 256) { float x = b[n]; s += x * x; }
    #pragma unroll
    for (int off = 32; off; off >>= 1) s += __shfl_down(s, off, 64);
    __shared__ float sp[4];
    if ((threadIdx.x & 63) == 0) sp[threadIdx.x >> 6] = s;
    __syncthreads();
    if (threadIdx.x == 0) ws[i] = sp[0] + sp[1] + sp[2] + sp[3];
}

// ---- build w-Toeplitz MFMA A-fragments into global table (row-independent) ----
__global__ __launch_bounds__(64) void prep_kernel(const float* __restrict__ w,
                                                  short* __restrict__ wtab)
{
    const int id   = blockIdx.x;          // 0..67 = layer*17 + ks
    const int layer = id / 17, ks = id % 17;
    const int lane = threadIdx.x;
    const int r    = lane & 15;
    const int kb   = ks * 32 + (lane >> 4) * 8;
    const float* wl = w + layer * 512;
    bf16x8 bb;
    #pragma unroll
    for (int jj = 0; jj < 8; ++jj) {
        const int idx = 512 + r - (kb + jj);
        const float val = (idx >= 0 && idx < 512) ? wl[idx] : 0.f;
        bb[jj] = f2b(val);
    }
    *(bf16x8*)(wtab + ((size_t)id * 64 + lane) * 8) = bb;
}

// ---- main fused kernel: one block per batch row; linear-g fragment scan ----
// R13: R11 + manual depth-4 rotating vf pipeline (named regs, literal-u slot
// select -> fully static). Tests the depth-1-serialization theory from R12's
// post-mortem. Everything else identical to R11.
__global__ __launch_bounds__(TB, 3) void hdcnn_kernel(
    const float* __restrict__ hk, const short* __restrict__ wtab,
    const float* __restrict__ bk0, const float* __restrict__ bk1,
    const float* __restrict__ bk2, const float* __restrict__ bk3,
    const float* __restrict__ y2w, float* __restrict__ out)
{
    __shared__ __align__(16) short svb[SVH];   // bf16 image of v, zero-padded
    __shared__ float sred[NW * 2];

    const int tid  = threadIdx.x;
    const int row  = blockIdx.x;
    const int lane = tid & 63;
    const int wv   = tid >> 6;
    const int jn   = lane & 15;
    const int kq   = lane >> 4;
    const int t0   = wv * TPW;                 // first tile of this wave

    // zero-fill sv image
    {
        int* svi = (int*)svb;
        for (int i = tid; i < SVH / 2; i += TB) svi[i] = 0;
    }
    __syncthreads();

    // layer-0 ingest: hk row -> bf16 at VOFFH
    {
        const float4* hrow = (const float4*)(hk + (size_t)row * 8192);
        for (int j = tid; j < 1024; j += TB) {
            float4 x0 = hrow[2 * j];
            float4 x1 = hrow[2 * j + 1];
            bf16x8 p;
            p[0] = f2b(x0.x); p[1] = f2b(x0.y); p[2] = f2b(x0.z); p[3] = f2b(x0.w);
            p[4] = f2b(x1.x); p[5] = f2b(x1.y); p[6] = f2b(x1.z); p[7] = f2b(x1.w);
            *(bf16x8*)(svb + VOFFH + 8 * j) = p;
        }
    }

    const int vbase = t0 * 256 + 16 * jn + 8 * kq;   // svb half-index base

    for (int layer = 0; layer < 4; ++layer) {
        const float* __restrict__ bk = (layer == 0) ? bk0 : (layer == 1) ? bk1
                                     : (layer == 2) ? bk2 : bk3;

        // w-Toeplitz A-fragments: 17 coalesced b128 loads from L2-hot table
        const short* wt = wtab + (size_t)layer * 8704 + lane * 8;
        bf16x8 wf[17];
        #pragma unroll
        for (int ks = 0; ks < 17; ++ks) wf[ks] = *(const bf16x8*)(wt + ks * 512);

        __syncthreads();   // svb (ingest or prev writeback) visible to all

        // linear fragment scan: g = 8*t0 + u; frag feeds tiles dt with ks=u-8*dt
        // Depth-4 rotating prefetch: read for step u issued at step u-4.
        f32x4 acc[TPW];
        #pragma unroll
        for (int dt = 0; dt < TPW; ++dt) acc[dt] = (f32x4){0.f, 0.f, 0.f, 0.f};

        bf16x8 vf0 = *(const bf16x8*)(svb + vbase);
        bf16x8 vf1 = *(const bf16x8*)(svb + vbase + 32);
        bf16x8 vf2 = *(const bf16x8*)(svb + vbase + 64);
        bf16x8 vf3 = *(const bf16x8*)(svb + vbase + 96);

        #pragma unroll
        for (int u = 0; u < UMAX; ++u) {
            // literal-u slot select: folds to a plain register reference
            bf16x8 cur;
            if ((u & 3) == 0)      cur = vf0;
            else if ((u & 3) == 1) cur = vf1;
            else if ((u & 3) == 2) cur = vf2;
            else                   cur = vf3;
            // refill this slot with the read for step u+4 (static slot, static addr)
            if (u + 4 < UMAX) {
                if ((u & 3) == 0)      vf0 = *(const bf16x8*)(svb + vbase + 32 * (u + 4));
                else if ((u & 3) == 1) vf1 = *(const bf16x8*)(svb + vbase + 32 * (u + 4));
                else if ((u & 3) == 2) vf2 = *(const bf16x8*)(svb + vbase + 32 * (u + 4));
                else                   vf3 = *(const bf16x8*)(svb + vbase + 32 * (u + 4));
            }
            const int dtlo = (u > 16) ? ((u - 9) >> 3) : 0;
            const int dthi = ((u >> 3) < TPW - 1) ? (u >> 3) : (TPW - 1);
            #pragma unroll
            for (int dt = dtlo; dt <= dthi; ++dt)
                acc[dt] = __builtin_amdgcn_mfma_f32_16x16x32_bf16(
                    wf[u - 8 * dt], cur, acc[dt], 0, 0, 0);
        }

        // row scalars: sum(conv^2), sum(conv*bk)
        float sum2 = 0.f, sxy = 0.f;
        #pragma unroll
        for (int dt = 0; dt < TPW; ++dt) {
            if (t0 + dt < 34) {
                const int nb = (t0 + dt) * 256 + 16 * jn + 4 * kq;
                float4 b4 = *(const float4*)(bk + nb);
                sum2 = fmaf(acc[dt][0], acc[dt][0], sum2);
                sum2 = fmaf(acc[dt][1], acc[dt][1], sum2);
                sum2 = fmaf(acc[dt][2], acc[dt][2], sum2);
                sum2 = fmaf(acc[dt][3], acc[dt][3], sum2);
                sxy  = fmaf(acc[dt][0], b4.x, sxy);
                sxy  = fmaf(acc[dt][1], b4.y, sxy);
                sxy  = fmaf(acc[dt][2], b4.z, sxy);
                sxy  = fmaf(acc[dt][3], b4.w, sxy);
            }
        }
        #pragma unroll
        for (int off = 32; off; off >>= 1) {
            sum2 += __shfl_down(sum2, off, 64);
            sxy  += __shfl_down(sxy,  off, 64);
        }
        if (lane == 0) { sred[wv * 2] = sum2; sred[wv * 2 + 1] = sxy; }
        __syncthreads();
        float un2 = 0.f, xys = 0.f;
        #pragma unroll
        for (int i = 0; i < NW; ++i) { un2 += sred[2 * i]; xys += sred[2 * i + 1]; }

        // hyperbolic scalars -> alpha, beta
        const float Cc  = 1e-12f;
        const float un  = sqrtf(un2);
        const float unc = fmaxf(un, 1e-15f);
        const float aa  = 1e-6f * unc;            // sqrt(c) * ||u||
        const float f   = tanhf(aa) / aa;         // expmap0 scale
        const float hn  = f * un;
        const float hnc = fmaxf(hn, 1e-15f);
        const float maxn = (1.0f - 0.004f) * 1.0e6f;
        const float s   = (hnc > maxn) ? f * (maxn / hnc) : f;  // proj scale
        const float x2  = s * s * un2;
        const float xy  = s * xys;
        const float y2  = y2w[layer];
        const float t2c = 2.f * Cc * xy;
        const float A   = 1.f + t2c + Cc * y2;
        const float B   = 1.f - Cc * x2;
        float D = 1.f + t2c + Cc * Cc * x2 * y2;
        D = fmaxf(D, 1e-15f);
        const float alpha = A * s / D;
        const float beta  = B / D;

        if (layer < 3) {
            // next v = relu(alpha*conv + beta*bk)[0:8192] as bf16
            #pragma unroll
            for (int dt = 0; dt < TPW; ++dt) {
                if (t0 + dt < 32) {
                    const int nb = (t0 + dt) * 256 + 16 * jn + 4 * kq;
                    float4 b4 = *(const float4*)(bk + nb);
                    short4 o;
                    o.x = f2b(fmaxf(alpha * acc[dt][0] + beta * b4.x, 0.f));
                    o.y = f2b(fmaxf(alpha * acc[dt][1] + beta * b4.y, 0.f));
                    o.z = f2b(fmaxf(alpha * acc[dt][2] + beta * b4.z, 0.f));
                    o.w = f2b(fmaxf(alpha * acc[dt][3] + beta * b4.w, 0.f));
                    *(short4*)(svb + VOFFH + nb) = o;
                }
            }
            // next layer's top barrier orders these writes before reads
        } else {
            float* orow = out + (size_t)row * 10240;
            #pragma unroll
            for (int dt = 0; dt < TPW; ++dt) {
                if (t0 + dt < 34) {
                    const int nb = (t0 + dt) * 256 + 16 * jn + 4 * kq;
                    float4 b4 = *(const float4*)(bk + nb);
                    float4 o;
                    o.x = fmaxf(alpha * acc[dt][0] + beta * b4.x, 0.f);
                    o.y = fmaxf(alpha * acc[dt][1] + beta * b4.y, 0.f);
                    o.z = fmaxf(alpha * acc[dt][2] + beta * b4.z, 0.f);
                    o.w = fmaxf(alpha * acc[dt][3] + beta * b4.w, 0.f);
                    *(float4*)(orow + nb) = o;
                }
            }
            for (int n = 8704 + 4 * tid; n < 10240; n += 4 * TB) {
                float4 b4 = *(const float4*)(bk + n);
                float4 o;
                o.x = fmaxf(beta * b4.x, 0.f);
                o.y = fmaxf(beta * b4.y, 0.f);
                o.z = fmaxf(beta * b4.z, 0.f);
                o.w = fmaxf(beta * b4.w, 0.f);
                *(float4*)(orow + n) = o;
            }
        }
    }
}

extern "C" void kernel_launch(void* const* d_in, const int* in_sizes, int n_in,
                              void* d_out, int out_size, void* d_ws, size_t ws_size,
                              hipStream_t stream) {
    const float* hk  = (const float*)d_in[0];
    const float* w   = (const float*)d_in[1];
    const float* bk0 = (const float*)d_in[2];
    const float* bk1 = (const float*)d_in[3];
    const float* bk2 = (const float*)d_in[4];
    const float* bk3 = (const float*)d_in[5];
    float* out = (float*)d_out;
    float* ws  = (float*)d_ws;          // [0..3]: y2 sums; +4: w-frag table
    short* wtab = (short*)(ws + 4);     // 68*64*8 halves = 69632 B

    y2_kernel<<<4, 256, 0, stream>>>(bk0, bk1, bk2, bk3, ws);
    prep_kernel<<<68, 64, 0, stream>>>(w, wtab);
    hdcnn_kernel<<<4096, TB, 0, stream>>>(hk, wtab, bk0, bk1, bk2, bk3, ws, out);
}

// Round 14
// 250.645 us; speedup vs baseline: 1.0395x; 1.0021x over previous
//
#include <hip/hip_runtime.h>
#include <hip/hip_bf16.h>
#include <math.h>

#define TB 256
#define NW 4                  // waves per block
#define TPW 9                 // tiles per wave (4*9=36 >= 34 real tiles)
#define VOFFH 512             // halves of zero pad below v[0]
#define SVH 9760              // bf16 halves in sv image
#define UMAX 81               // 8*(TPW-1)+17 fragment steps per wave
#define UCUT 65               // wave 3's last real tile (33) completes at u=64

typedef __attribute__((ext_vector_type(8))) short bf16x8;
typedef __attribute__((ext_vector_type(4))) float f32x4;

__device__ __forceinline__ short f2b(float x) {
    union { __hip_bfloat16 h; short s; } u;
    u.h = __float2bfloat16(x);
    return u.s;
}

// ---- per-layer sum(bk^2) into ws[0..3] ----
__global__ __launch_bounds__(256) void y2_kernel(
    const float* __restrict__ bk0, const float* __restrict__ bk1,
    const float* __restrict__ bk2, const float* __restrict__ bk3,
    float* __restrict__ ws)
{
    const float* bks[4] = {bk0, bk1, bk2, bk3};
    const int i = blockIdx.x;
    const int L = 8192 + (i + 1) * 512;
    const float* b = bks[i];
    float s = 0.f;
    for (int n = threadIdx.x; n < L; n += 256) { float x = b[n]; s += x * x; }
    #pragma unroll
    for (int off = 32; off; off >>= 1) s += __shfl_down(s, off, 64);
    __shared__ float sp[4];
    if ((threadIdx.x & 63) == 0) sp[threadIdx.x >> 6] = s;
    __syncthreads();
    if (threadIdx.x == 0) ws[i] = sp[0] + sp[1] + sp[2] + sp[3];
}

// ---- build w-Toeplitz MFMA A-fragments into global table (row-independent) ----
__global__ __launch_bounds__(64) void prep_kernel(const float* __restrict__ w,
                                                  short* __restrict__ wtab)
{
    const int id   = blockIdx.x;          // 0..67 = layer*17 + ks
    const int layer = id / 17, ks = id % 17;
    const int lane = threadIdx.x;
    const int r    = lane & 15;
    const int kb   = ks * 32 + (lane >> 4) * 8;
    const float* wl = w + layer * 512;
    bf16x8 bb;
    #pragma unroll
    for (int jj = 0; jj < 8; ++jj) {
        const int idx = 512 + r - (kb + jj);
        const float val = (idx >= 0 && idx < 512) ? wl[idx] : 0.f;
        bb[jj] = f2b(val);
    }
    *(bf16x8*)(wtab + ((size_t)id * 64 + lane) * 8) = bb;
}

// ---- main fused kernel: one block per batch row; linear-g fragment scan ----
// R14: R11 + launch_bounds(256,4) (target 128 regs -> 4 waves/SIMD -> 16
// waves/CU) + phantom-tail trim (wave 3 skips u=65..80 via a wave-uniform
// branch around a statically-indexed unrolled block).
__global__ __launch_bounds__(TB, 4) void hdcnn_kernel(
    const float* __restrict__ hk, const short* __restrict__ wtab,
    const float* __restrict__ bk0, const float* __restrict__ bk1,
    const float* __restrict__ bk2, const float* __restrict__ bk3,
    const float* __restrict__ y2w, float* __restrict__ out)
{
    __shared__ __align__(16) short svb[SVH];   // bf16 image of v, zero-padded
    __shared__ float sred[NW * 2];

    const int tid  = threadIdx.x;
    const int row  = blockIdx.x;
    const int lane = tid & 63;
    const int wv   = tid >> 6;
    const int jn   = lane & 15;
    const int kq   = lane >> 4;
    const int t0   = wv * TPW;                 // first tile of this wave

    // zero-fill sv image
    {
        int* svi = (int*)svb;
        for (int i = tid; i < SVH / 2; i += TB) svi[i] = 0;
    }
    __syncthreads();

    // layer-0 ingest: hk row -> bf16 at VOFFH
    {
        const float4* hrow = (const float4*)(hk + (size_t)row * 8192);
        for (int j = tid; j < 1024; j += TB) {
            float4 x0 = hrow[2 * j];
            float4 x1 = hrow[2 * j + 1];
            bf16x8 p;
            p[0] = f2b(x0.x); p[1] = f2b(x0.y); p[2] = f2b(x0.z); p[3] = f2b(x0.w);
            p[4] = f2b(x1.x); p[5] = f2b(x1.y); p[6] = f2b(x1.z); p[7] = f2b(x1.w);
            *(bf16x8*)(svb + VOFFH + 8 * j) = p;
        }
    }

    const int vbase = t0 * 256 + 16 * jn + 8 * kq;   // svb half-index base

    for (int layer = 0; layer < 4; ++layer) {
        const float* __restrict__ bk = (layer == 0) ? bk0 : (layer == 1) ? bk1
                                     : (layer == 2) ? bk2 : bk3;

        // w-Toeplitz A-fragments: 17 coalesced b128 loads from L2-hot table
        const short* wt = wtab + (size_t)layer * 8704 + lane * 8;
        bf16x8 wf[17];
        #pragma unroll
        for (int ks = 0; ks < 17; ++ks) wf[ks] = *(const bf16x8*)(wt + ks * 512);

        __syncthreads();   // svb (ingest or prev writeback) visible to all

        // linear fragment scan: g = 8*t0 + u; frag feeds tiles dt with ks=u-8*dt
        // Fully static inside each block; wave-uniform branch AROUND the tail.
        f32x4 acc[TPW];
        #pragma unroll
        for (int dt = 0; dt < TPW; ++dt) acc[dt] = (f32x4){0.f, 0.f, 0.f, 0.f};

        #pragma unroll
        for (int u = 0; u < UCUT; ++u) {
            bf16x8 vf = *(const bf16x8*)(svb + vbase + 32 * u);
            const int dtlo = (u > 16) ? ((u - 9) >> 3) : 0;
            const int dthi = ((u >> 3) < TPW - 1) ? (u >> 3) : (TPW - 1);
            #pragma unroll
            for (int dt = dtlo; dt <= dthi; ++dt)
                acc[dt] = __builtin_amdgcn_mfma_f32_16x16x32_bf16(
                    wf[u - 8 * dt], vf, acc[dt], 0, 0, 0);
        }
        if (wv < 3) {   // wave-uniform: wave 3's tiles 34/35 are phantom
            #pragma unroll
            for (int u = UCUT; u < UMAX; ++u) {
                bf16x8 vf = *(const bf16x8*)(svb + vbase + 32 * u);
                const int dtlo = (u - 9) >> 3;
                const int dthi = TPW - 1;
                #pragma unroll
                for (int dt = dtlo; dt <= dthi; ++dt)
                    acc[dt] = __builtin_amdgcn_mfma_f32_16x16x32_bf16(
                        wf[u - 8 * dt], vf, acc[dt], 0, 0, 0);
            }
        }

        // row scalars: sum(conv^2), sum(conv*bk)
        float sum2 = 0.f, sxy = 0.f;
        #pragma unroll
        for (int dt = 0; dt < TPW; ++dt) {
            if (t0 + dt < 34) {
                const int nb = (t0 + dt) * 256 + 16 * jn + 4 * kq;
                float4 b4 = *(const float4*)(bk + nb);
                sum2 = fmaf(acc[dt][0], acc[dt][0], sum2);
                sum2 = fmaf(acc[dt][1], acc[dt][1], sum2);
                sum2 = fmaf(acc[dt][2], acc[dt][2], sum2);
                sum2 = fmaf(acc[dt][3], acc[dt][3], sum2);
                sxy  = fmaf(acc[dt][0], b4.x, sxy);
                sxy  = fmaf(acc[dt][1], b4.y, sxy);
                sxy  = fmaf(acc[dt][2], b4.z, sxy);
                sxy  = fmaf(acc[dt][3], b4.w, sxy);
            }
        }
        #pragma unroll
        for (int off = 32; off; off >>= 1) {
            sum2 += __shfl_down(sum2, off, 64);
            sxy  += __shfl_down(sxy,  off, 64);
        }
        if (lane == 0) { sred[wv * 2] = sum2; sred[wv * 2 + 1] = sxy; }
        __syncthreads();
        float un2 = 0.f, xys = 0.f;
        #pragma unroll
        for (int i = 0; i < NW; ++i) { un2 += sred[2 * i]; xys += sred[2 * i + 1]; }

        // hyperbolic scalars -> alpha, beta
        const float Cc  = 1e-12f;
        const float un  = sqrtf(un2);
        const float unc = fmaxf(un, 1e-15f);
        const float aa  = 1e-6f * unc;            // sqrt(c) * ||u||
        const float f   = tanhf(aa) / aa;         // expmap0 scale
        const float hn  = f * un;
        const float hnc = fmaxf(hn, 1e-15f);
        const float maxn = (1.0f - 0.004f) * 1.0e6f;
        const float s   = (hnc > maxn) ? f * (maxn / hnc) : f;  // proj scale
        const float x2  = s * s * un2;
        const float xy  = s * xys;
        const float y2  = y2w[layer];
        const float t2c = 2.f * Cc * xy;
        const float A   = 1.f + t2c + Cc * y2;
        const float B   = 1.f - Cc * x2;
        float D = 1.f + t2c + Cc * Cc * x2 * y2;
        D = fmaxf(D, 1e-15f);
        const float alpha = A * s / D;
        const float beta  = B / D;

        if (layer < 3) {
            // next v = relu(alpha*conv + beta*bk)[0:8192] as bf16
            #pragma unroll
            for (int dt = 0; dt < TPW; ++dt) {
                if (t0 + dt < 32) {
                    const int nb = (t0 + dt) * 256 + 16 * jn + 4 * kq;
                    float4 b4 = *(const float4*)(bk + nb);
                    short4 o;
                    o.x = f2b(fmaxf(alpha * acc[dt][0] + beta * b4.x, 0.f));
                    o.y = f2b(fmaxf(alpha * acc[dt][1] + beta * b4.y, 0.f));
                    o.z = f2b(fmaxf(alpha * acc[dt][2] + beta * b4.z, 0.f));
                    o.w = f2b(fmaxf(alpha * acc[dt][3] + beta * b4.w, 0.f));
                    *(short4*)(svb + VOFFH + nb) = o;
                }
            }
            // next layer's top barrier orders these writes before reads
        } else {
            float* orow = out + (size_t)row * 10240;
            #pragma unroll
            for (int dt = 0; dt < TPW; ++dt) {
                if (t0 + dt < 34) {
                    const int nb = (t0 + dt) * 256 + 16 * jn + 4 * kq;
                    float4 b4 = *(const float4*)(bk + nb);
                    float4 o;
                    o.x = fmaxf(alpha * acc[dt][0] + beta * b4.x, 0.f);
                    o.y = fmaxf(alpha * acc[dt][1] + beta * b4.y, 0.f);
                    o.z = fmaxf(alpha * acc[dt][2] + beta * b4.z, 0.f);
                    o.w = fmaxf(alpha * acc[dt][3] + beta * b4.w, 0.f);
                    *(float4*)(orow + nb) = o;
                }
            }
            for (int n = 8704 + 4 * tid; n < 10240; n += 4 * TB) {
                float4 b4 = *(const float4*)(bk + n);
                float4 o;
                o.x = fmaxf(beta * b4.x, 0.f);
                o.y = fmaxf(beta * b4.y, 0.f);
                o.z = fmaxf(beta * b4.z, 0.f);
                o.w = fmaxf(beta * b4.w, 0.f);
                *(float4*)(orow + n) = o;
            }
        }
    }
}

extern "C" void kernel_launch(void* const* d_in, const int* in_sizes, int n_in,
                              void* d_out, int out_size, void* d_ws, size_t ws_size,
                              hipStream_t stream) {
    const float* hk  = (const float*)d_in[0];
    const float* w   = (const float*)d_in[1];
    const float* bk0 = (const float*)d_in[2];
    const float* bk1 = (const float*)d_in[3];
    const float* bk2 = (const float*)d_in[4];
    const float* bk3 = (const float*)d_in[5];
    float* out = (float*)d_out;
    float* ws  = (float*)d_ws;          // [0..3]: y2 sums; +4: w-frag table
    short* wtab = (short*)(ws + 4);     // 68*64*8 halves = 69632 B

    y2_kernel<<<4, 256, 0, stream>>>(bk0, bk1, bk2, bk3, ws);
    prep_kernel<<<68, 64, 0, stream>>>(w, wtab);
    hdcnn_kernel<<<4096, TB, 0, stream>>>(hk, wtab, bk0, bk1, bk2, bk3, ws, out);
}

// Round 15
// 226.148 us; speedup vs baseline: 1.1521x; 1.1083x over previous
//
#include <hip/hip_runtime.h>
#include <hip/hip_bf16.h>
#include <math.h>

#define TB 256
#define NW 4                  // waves per block
#define TPW 9                 // tiles per wave (4*9=36 >= 34 real tiles)
#define VOFFH 512             // halves of zero pad below v[0]
#define SVH 9760              // bf16 halves in sv image (max read idx 9744)
#define UMAX 81               // 8*(TPW-1)+17 fragment steps per wave
#define UCUT 65               // wave 3's last real tile (33) completes at u=64

typedef __attribute__((ext_vector_type(8))) short bf16x8;
typedef __attribute__((ext_vector_type(4))) float f32x4;

__device__ __forceinline__ short f2b(float x) {
    union { __hip_bfloat16 h; short s; } u;
    u.h = __float2bfloat16(x);
    return u.s;
}

// ---- per-layer sum(bk^2) into ws[0..3] ----
__global__ __launch_bounds__(256) void y2_kernel(
    const float* __restrict__ bk0, const float* __restrict__ bk1,
    const float* __restrict__ bk2, const float* __restrict__ bk3,
    float* __restrict__ ws)
{
    const float* bks[4] = {bk0, bk1, bk2, bk3};
    const int i = blockIdx.x;
    const int L = 8192 + (i + 1) * 512;
    const float* b = bks[i];
    float s = 0.f;
    for (int n = threadIdx.x; n < L; n += 256) { float x = b[n]; s += x * x; }
    #pragma unroll
    for (int off = 32; off; off >>= 1) s += __shfl_down(s, off, 64);
    __shared__ float sp[4];
    if ((threadIdx.x & 63) == 0) sp[threadIdx.x >> 6] = s;
    __syncthreads();
    if (threadIdx.x == 0) ws[i] = sp[0] + sp[1] + sp[2] + sp[3];
}

// ---- build w-Toeplitz MFMA A-fragments into global table (row-independent) ----
__global__ __launch_bounds__(64) void prep_kernel(const float* __restrict__ w,
                                                  short* __restrict__ wtab)
{
    const int id   = blockIdx.x;          // 0..67 = layer*17 + ks
    const int layer = id / 17, ks = id % 17;
    const int lane = threadIdx.x;
    const int r    = lane & 15;
    const int kb   = ks * 32 + (lane >> 4) * 8;
    const float* wl = w + layer * 512;
    bf16x8 bb;
    #pragma unroll
    for (int jj = 0; jj < 8; ++jj) {
        const int idx = 512 + r - (kb + jj);
        const float val = (idx >= 0 && idx < 512) ? wl[idx] : 0.f;
        bb[jj] = f2b(val);
    }
    *(bf16x8*)(wtab + ((size_t)id * 64 + lane) * 8) = bb;
}

// ---- main fused kernel: one block per batch row; linear-g fragment scan ----
// R15 = R11 exact (launch_bounds(256,3), the 230us config) + phantom-tail trim
// (wave 3 skips u=65..80; tiles 34/35 are fake). Register-neutral per R14.
__global__ __launch_bounds__(TB, 3) void hdcnn_kernel(
    const float* __restrict__ hk, const short* __restrict__ wtab,
    const float* __restrict__ bk0, const float* __restrict__ bk1,
    const float* __restrict__ bk2, const float* __restrict__ bk3,
    const float* __restrict__ y2w, float* __restrict__ out)
{
    __shared__ __align__(16) short svb[SVH];   // bf16 image of v, zero-padded
    __shared__ float sred[NW * 2];

    const int tid  = threadIdx.x;
    const int row  = blockIdx.x;
    const int lane = tid & 63;
    const int wv   = tid >> 6;
    const int jn   = lane & 15;
    const int kq   = lane >> 4;
    const int t0   = wv * TPW;                 // first tile of this wave

    // zero-fill sv image
    {
        int* svi = (int*)svb;
        for (int i = tid; i < SVH / 2; i += TB) svi[i] = 0;
    }
    __syncthreads();

    // layer-0 ingest: hk row -> bf16 at VOFFH
    {
        const float4* hrow = (const float4*)(hk + (size_t)row * 8192);
        for (int j = tid; j < 1024; j += TB) {
            float4 x0 = hrow[2 * j];
            float4 x1 = hrow[2 * j + 1];
            bf16x8 p;
            p[0] = f2b(x0.x); p[1] = f2b(x0.y); p[2] = f2b(x0.z); p[3] = f2b(x0.w);
            p[4] = f2b(x1.x); p[5] = f2b(x1.y); p[6] = f2b(x1.z); p[7] = f2b(x1.w);
            *(bf16x8*)(svb + VOFFH + 8 * j) = p;
        }
    }

    const int vbase = t0 * 256 + 16 * jn + 8 * kq;   // svb half-index base

    for (int layer = 0; layer < 4; ++layer) {
        const float* __restrict__ bk = (layer == 0) ? bk0 : (layer == 1) ? bk1
                                     : (layer == 2) ? bk2 : bk3;

        // w-Toeplitz A-fragments: 17 coalesced b128 loads from L2-hot table
        const short* wt = wtab + (size_t)layer * 8704 + lane * 8;
        bf16x8 wf[17];
        #pragma unroll
        for (int ks = 0; ks < 17; ++ks) wf[ks] = *(const bf16x8*)(wt + ks * 512);

        __syncthreads();   // svb (ingest or prev writeback) visible to all

        // linear fragment scan: g = 8*t0 + u; frag feeds tiles dt with ks=u-8*dt
        // Fully static inside each block; wave-uniform branch AROUND the tail.
        f32x4 acc[TPW];
        #pragma unroll
        for (int dt = 0; dt < TPW; ++dt) acc[dt] = (f32x4){0.f, 0.f, 0.f, 0.f};

        #pragma unroll
        for (int u = 0; u < UCUT; ++u) {
            bf16x8 vf = *(const bf16x8*)(svb + vbase + 32 * u);
            const int dtlo = (u > 16) ? ((u - 9) >> 3) : 0;
            const int dthi = ((u >> 3) < TPW - 1) ? (u >> 3) : (TPW - 1);
            #pragma unroll
            for (int dt = dtlo; dt <= dthi; ++dt)
                acc[dt] = __builtin_amdgcn_mfma_f32_16x16x32_bf16(
                    wf[u - 8 * dt], vf, acc[dt], 0, 0, 0);
        }
        if (wv < 3) {   // wave-uniform: wave 3's tiles 34/35 are phantom
            #pragma unroll
            for (int u = UCUT; u < UMAX; ++u) {
                bf16x8 vf = *(const bf16x8*)(svb + vbase + 32 * u);
                const int dtlo = (u - 9) >> 3;
                const int dthi = TPW - 1;
                #pragma unroll
                for (int dt = dtlo; dt <= dthi; ++dt)
                    acc[dt] = __builtin_amdgcn_mfma_f32_16x16x32_bf16(
                        wf[u - 8 * dt], vf, acc[dt], 0, 0, 0);
            }
        }

        // row scalars: sum(conv^2), sum(conv*bk)
        float sum2 = 0.f, sxy = 0.f;
        #pragma unroll
        for (int dt = 0; dt < TPW; ++dt) {
            if (t0 + dt < 34) {
                const int nb = (t0 + dt) * 256 + 16 * jn + 4 * kq;
                float4 b4 = *(const float4*)(bk + nb);
                sum2 = fmaf(acc[dt][0], acc[dt][0], sum2);
                sum2 = fmaf(acc[dt][1], acc[dt][1], sum2);
                sum2 = fmaf(acc[dt][2], acc[dt][2], sum2);
                sum2 = fmaf(acc[dt][3], acc[dt][3], sum2);
                sxy  = fmaf(acc[dt][0], b4.x, sxy);
                sxy  = fmaf(acc[dt][1], b4.y, sxy);
                sxy  = fmaf(acc[dt][2], b4.z, sxy);
                sxy  = fmaf(acc[dt][3], b4.w, sxy);
            }
        }
        #pragma unroll
        for (int off = 32; off; off >>= 1) {
            sum2 += __shfl_down(sum2, off, 64);
            sxy  += __shfl_down(sxy,  off, 64);
        }
        if (lane == 0) { sred[wv * 2] = sum2; sred[wv * 2 + 1] = sxy; }
        __syncthreads();
        float un2 = 0.f, xys = 0.f;
        #pragma unroll
        for (int i = 0; i < NW; ++i) { un2 += sred[2 * i]; xys += sred[2 * i + 1]; }

        // hyperbolic scalars -> alpha, beta
        const float Cc  = 1e-12f;
        const float un  = sqrtf(un2);
        const float unc = fmaxf(un, 1e-15f);
        const float aa  = 1e-6f * unc;            // sqrt(c) * ||u||
        const float f   = tanhf(aa) / aa;         // expmap0 scale
        const float hn  = f * un;
        const float hnc = fmaxf(hn, 1e-15f);
        const float maxn = (1.0f - 0.004f) * 1.0e6f;
        const float s   = (hnc > maxn) ? f * (maxn / hnc) : f;  // proj scale
        const float x2  = s * s * un2;
        const float xy  = s * xys;
        const float y2  = y2w[layer];
        const float t2c = 2.f * Cc * xy;
        const float A   = 1.f + t2c + Cc * y2;
        const float B   = 1.f - Cc * x2;
        float D = 1.f + t2c + Cc * Cc * x2 * y2;
        D = fmaxf(D, 1e-15f);
        const float alpha = A * s / D;
        const float beta  = B / D;

        if (layer < 3) {
            // next v = relu(alpha*conv + beta*bk)[0:8192] as bf16
            #pragma unroll
            for (int dt = 0; dt < TPW; ++dt) {
                if (t0 + dt < 32) {
                    const int nb = (t0 + dt) * 256 + 16 * jn + 4 * kq;
                    float4 b4 = *(const float4*)(bk + nb);
                    short4 o;
                    o.x = f2b(fmaxf(alpha * acc[dt][0] + beta * b4.x, 0.f));
                    o.y = f2b(fmaxf(alpha * acc[dt][1] + beta * b4.y, 0.f));
                    o.z = f2b(fmaxf(alpha * acc[dt][2] + beta * b4.z, 0.f));
                    o.w = f2b(fmaxf(alpha * acc[dt][3] + beta * b4.w, 0.f));
                    *(short4*)(svb + VOFFH + nb) = o;
                }
            }
            // next layer's top barrier orders these writes before reads
        } else {
            float* orow = out + (size_t)row * 10240;
            #pragma unroll
            for (int dt = 0; dt < TPW; ++dt) {
                if (t0 + dt < 34) {
                    const int nb = (t0 + dt) * 256 + 16 * jn + 4 * kq;
                    float4 b4 = *(const float4*)(bk + nb);
                    float4 o;
                    o.x = fmaxf(alpha * acc[dt][0] + beta * b4.x, 0.f);
                    o.y = fmaxf(alpha * acc[dt][1] + beta * b4.y, 0.f);
                    o.z = fmaxf(alpha * acc[dt][2] + beta * b4.z, 0.f);
                    o.w = fmaxf(alpha * acc[dt][3] + beta * b4.w, 0.f);
                    *(float4*)(orow + nb) = o;
                }
            }
            for (int n = 8704 + 4 * tid; n < 10240; n += 4 * TB) {
                float4 b4 = *(const float4*)(bk + n);
                float4 o;
                o.x = fmaxf(beta * b4.x, 0.f);
                o.y = fmaxf(beta * b4.y, 0.f);
                o.z = fmaxf(beta * b4.z, 0.f);
                o.w = fmaxf(beta * b4.w, 0.f);
                *(float4*)(orow + n) = o;
            }
        }
    }
}

extern "C" void kernel_launch(void* const* d_in, const int* in_sizes, int n_in,
                              void* d_out, int out_size, void* d_ws, size_t ws_size,
                              hipStream_t stream) {
    const float* hk  = (const float*)d_in[0];
    const float* w   = (const float*)d_in[1];
    const float* bk0 = (const float*)d_in[2];
    const float* bk1 = (const float*)d_in[3];
    const float* bk2 = (const float*)d_in[4];
    const float* bk3 = (const float*)d_in[5];
    float* out = (float*)d_out;
    float* ws  = (float*)d_ws;          // [0..3]: y2 sums; +4: w-frag table
    short* wtab = (short*)(ws + 4);     // 68*64*8 halves = 69632 B

    y2_kernel<<<4, 256, 0, stream>>>(bk0, bk1, bk2, bk3, ws);
    prep_kernel<<<68, 64, 0, stream>>>(w, wtab);
    hdcnn_kernel<<<4096, TB, 0, stream>>>(hk, wtab, bk0, bk1, bk2, bk3, ws, out);
}